// Round 6
// baseline (457.414 us; speedup 1.0000x reference)
//
#include <hip/hip_runtime.h>
#include <hip/hip_bf16.h>

#define N_NODES 50000
#define N_EDGES 800000
#define M_IN 512
#define H_OUT 512

typedef __attribute__((ext_vector_type(8))) short    bf16x8;  // MFMA A/B frag (4 VGPR)
typedef __attribute__((ext_vector_type(4))) float    f32x4;   // MFMA C/D frag
typedef __attribute__((ext_vector_type(8))) unsigned short u16x8;

__device__ inline float bf2f(unsigned short u) {
    unsigned int x = ((unsigned int)u) << 16;
    return __builtin_bit_cast(float, x);
}
__device__ inline unsigned short f2bf(float f) {   // round-to-nearest-even
    unsigned int x = __builtin_bit_cast(unsigned int, f);
    return (unsigned short)((x + 0x7FFF + ((x >> 16) & 1)) >> 16);
}
__device__ inline void gload_lds16(const void* g, void* lds) {
    __builtin_amdgcn_global_load_lds(
        (const __attribute__((address_space(1))) void*)g,
        (__attribute__((address_space(3))) void*)lds, 16, 0, 0);
}

// ---------------------------------------------------------------------------
// prep: fused convx (blocks [0,12500)) + convw + hist. All independent.
// ---------------------------------------------------------------------------
#define CONVX_B 12500
#define CONVW_B 1024
#define HIST_B  3125

__global__ __launch_bounds__(256) void prep_kernel(
    const float* __restrict__ X, unsigned short* __restrict__ Xb,
    const float* __restrict__ W, unsigned short* __restrict__ Wt,
    const int* __restrict__ edst, int* __restrict__ counts)
{
    const int b = blockIdx.x;
    if (b < CONVX_B) {
        const size_t i = (size_t)b * 256 + threadIdx.x;        // 3.2M threads x 8 f32
        const float4 a = ((const float4*)X)[2 * i];
        const float4 c = ((const float4*)X)[2 * i + 1];
        u16x8 o;
        o[0] = f2bf(a.x); o[1] = f2bf(a.y); o[2] = f2bf(a.z); o[3] = f2bf(a.w);
        o[4] = f2bf(c.x); o[5] = f2bf(c.y); o[6] = f2bf(c.z); o[7] = f2bf(c.w);
        *(u16x8*)(Xb + i * 8) = o;
    } else if (b < CONVX_B + CONVW_B) {
        const int id = (b - CONVX_B) * 256 + threadIdx.x;      // 262144 = 512*512
        const int n = id >> 9, k = id & 511;
        Wt[(size_t)n * 512 + k] = f2bf(W[(size_t)k * 512 + n]);
    } else {
        const int e = (b - CONVX_B - CONVW_B) * 256 + threadIdx.x;  // 800000 exact
        atomicAdd(&counts[edst[e]], 1);
    }
}

// ---------------------------------------------------------------------------
// scan: 1024-thread single-block exclusive scan of counts -> offs[0..N];
// also zeroes counts (reused as build cursor).
// ---------------------------------------------------------------------------
__global__ __launch_bounds__(1024) void scan_kernel(
    int* __restrict__ counts, int* __restrict__ offs)
{
    __shared__ int wsum[16];
    const int tid  = threadIdx.x;
    const int lane = tid & 63;
    const int wv   = tid >> 6;
    const int CH   = (N_NODES + 1023) / 1024;   // 49
    const int b    = tid * CH;
    const int e    = min(b + CH, N_NODES);

    int s = 0;
    for (int i = b; i < e; ++i) s += counts[i];

    int x = s;
#pragma unroll
    for (int d = 1; d < 64; d <<= 1) {
        int y = __shfl_up(x, d, 64);
        if (lane >= d) x += y;
    }
    if (lane == 63) wsum[wv] = x;
    __syncthreads();
    if (tid == 0) {
        int run = 0;
#pragma unroll
        for (int i = 0; i < 16; ++i) { int t = wsum[i]; wsum[i] = run; run += t; }
    }
    __syncthreads();

    int run = wsum[wv] + (x - s);
    for (int i = b; i < e; ++i) {
        int c = counts[i];
        offs[i]   = run;
        counts[i] = 0;
        run += c;
    }
    if (e == N_NODES) offs[N_NODES] = run;
}

// build: packed edge = (src16 << 16) | bf16(val) — 4B random store per edge.
// src < 50000 < 65536 fits 16 bits; bf16 val rel-err ~0.2% (negligible).
__global__ __launch_bounds__(256) void build_kernel(
    const int* __restrict__ esrc, const int* __restrict__ edst,
    const float* __restrict__ eval,
    const int* __restrict__ offs, int* __restrict__ cursor,
    unsigned int* __restrict__ pairs)
{
    const int e = blockIdx.x * 256 + threadIdx.x;
    if (e >= N_EDGES) return;
    const int d   = edst[e];
    const int pos = offs[d] + atomicAdd(&cursor[d], 1);
    pairs[pos] = ((unsigned int)esrc[e] << 16) | (unsigned int)f2bf(eval[e]);
}

// ---------------------------------------------------------------------------
// Gather v3: column-sliced, XCD-pinned. 16 col-groups of 32 cols (64 B/row):
// per (slice,pass) the X working set is 50000*64B = 3.2 MB < 4 MB per-XCD L2.
// slice = blockIdx%8 pins a slice to an XCD (round-robin dispatch heuristic).
// Wave layout: lane = nd*4+ch -> 16 nodes/wave, each lane accumulates 8 cols
// for its node (no cross-lane reduce). Two sequential passes (kernel arg).
// ---------------------------------------------------------------------------
__global__ __launch_bounds__(256) void gather_kernel(
    const unsigned short* __restrict__ Xb,
    const int*          __restrict__ offs,
    const unsigned int* __restrict__ pairs,
    unsigned short*     __restrict__ Yb,
    int pass)
{
    const int slice = blockIdx.x & 7;          // -> XCD
    const int ngrp  = blockIdx.x >> 3;
    const int wid   = threadIdx.x >> 6;
    const int lane  = threadIdx.x & 63;
    const int nd    = lane >> 2;               // node-sub 0..15
    const int ch    = lane & 3;                // 16B chunk 0..3
    const int node  = (ngrp * 4 + wid) * 16 + nd;
    if (node >= N_NODES) return;

    const int g     = pass * 8 + slice;        // col group 0..15
    const int colel = g * 32 + ch * 8;         // first of this lane's 8 cols
    const unsigned short* __restrict__ xcol = Xb + colel;

    const int beg = offs[node];
    const int end = offs[node + 1];

    float acc[8] = {};

    int e = beg;
    while (__any(e < end)) {
        if (e < end) {
            const unsigned int pk = pairs[e];
            const float v = bf2f((unsigned short)(pk & 0xffffu));
            const u16x8 x = *(const u16x8*)(xcol + (size_t)(pk >> 16) * M_IN);
#pragma unroll
            for (int j = 0; j < 8; ++j) acc[j] += bf2f(x[j]) * v;
        }
        if (e + 1 < end) {
            const unsigned int pk = pairs[e + 1];
            const float v = bf2f((unsigned short)(pk & 0xffffu));
            const u16x8 x = *(const u16x8*)(xcol + (size_t)(pk >> 16) * M_IN);
#pragma unroll
            for (int j = 0; j < 8; ++j) acc[j] += bf2f(x[j]) * v;
        }
        e += 2;
    }

    u16x8 o;
#pragma unroll
    for (int j = 0; j < 8; ++j) o[j] = f2bf(acc[j]);
    *(u16x8*)(Yb + (size_t)node * M_IN + colel) = o;
}

// ---------------------------------------------------------------------------
// out = relu(Yb @ Wt^T) — bf16 MFMA 16x16x32, fp32 accum. (unchanged round 5)
// 128x128 tile, BK=32, 4 waves, 2-phase double-buffered pipeline.
// ---------------------------------------------------------------------------
#define BM 128
#define BN 128
#define BK 32
#define NT (M_IN / BK)   // 16

__global__ __launch_bounds__(256, 2) void gemm_mfma_kernel(
    const unsigned short* __restrict__ Yb,
    const unsigned short* __restrict__ Wt,
    float* __restrict__ out)
{
    __shared__ unsigned short As[2][BM * BK];  // 2 x 8 KB
    __shared__ unsigned short Bs[2][BN * BK];  // 2 x 8 KB

    const int tid  = threadIdx.x;
    const int lane = tid & 63;
    const int wid  = tid >> 6;
    const int wr   = wid >> 1;
    const int wc   = wid & 1;
    const int row0 = blockIdx.y * BM;
    const int col0 = blockIdx.x * BN;

    f32x4 acc[4][4] = {};

    int srow[2], ksw[2], ldsb[2];
#pragma unroll
    for (int i = 0; i < 2; ++i) {
        const int b   = (i * 256 + tid) * 16;
        const int row = b >> 6;
        const int cir = (b >> 4) & 3;
        srow[i] = row;
        ksw[i]  = (cir ^ ((row >> 1) & 3)) << 3;
        ldsb[i] = b;
    }
    int agr[2];
#pragma unroll
    for (int i = 0; i < 2; ++i) {
        int gr = row0 + srow[i];
        if (gr >= N_NODES) gr = N_NODES - 1;
        agr[i] = gr;
    }

    int abyte[4], bbyte[4];
    const int c = lane >> 4;
#pragma unroll
    for (int m = 0; m < 4; ++m) {
        const int ra = wr * 64 + m * 16 + (lane & 15);
        abyte[m] = ra * 64 + ((c ^ ((ra >> 1) & 3)) << 4);
        const int rb = wc * 64 + m * 16 + (lane & 15);
        bbyte[m] = rb * 64 + ((c ^ ((rb >> 1) & 3)) << 4);
    }

#define STAGE(buf, k0)                                                          \
    do {                                                                        \
        _Pragma("unroll")                                                       \
        for (int i = 0; i < 2; ++i) {                                           \
            gload_lds16(Yb + (size_t)agr[i] * M_IN + (k0) + ksw[i],             \
                        (char*)As[buf] + ldsb[i]);                              \
            gload_lds16(Wt + (size_t)(col0 + srow[i]) * M_IN + (k0) + ksw[i],   \
                        (char*)Bs[buf] + ldsb[i]);                              \
        }                                                                       \
    } while (0)

    STAGE(0, 0);
    asm volatile("s_waitcnt vmcnt(0)" ::: "memory");
    __builtin_amdgcn_s_barrier();

    int cur = 0;
    for (int t = 0; t < NT; ++t) {
        if (t + 1 < NT) STAGE(cur ^ 1, (t + 1) * BK);

        bf16x8 af[4], bfr[4];
#pragma unroll
        for (int m = 0; m < 4; ++m)
            af[m]  = *(const bf16x8*)((const char*)As[cur] + abyte[m]);
#pragma unroll
        for (int n = 0; n < 4; ++n)
            bfr[n] = *(const bf16x8*)((const char*)Bs[cur] + bbyte[n]);

#pragma unroll
        for (int m = 0; m < 4; ++m)
#pragma unroll
            for (int n = 0; n < 4; ++n)
                acc[m][n] = __builtin_amdgcn_mfma_f32_16x16x32_bf16(
                    af[m], bfr[n], acc[m][n], 0, 0, 0);

        if (t + 1 < NT) {
            asm volatile("s_waitcnt vmcnt(0)" ::: "memory");
            __builtin_amdgcn_s_barrier();
        }
        cur ^= 1;
    }
#undef STAGE

    // epilogue: C/D map col=lane&15, row=(lane>>4)*4+r  [measured m89]
#pragma unroll
    for (int m = 0; m < 4; ++m) {
#pragma unroll
        for (int n = 0; n < 4; ++n) {
#pragma unroll
            for (int r = 0; r < 4; ++r) {
                const int row = row0 + wr * 64 + m * 16 + (lane >> 4) * 4 + r;
                const int col = col0 + wc * 64 + n * 16 + (lane & 15);
                if (row < N_NODES)
                    out[(size_t)row * H_OUT + col] = fmaxf(acc[m][n][r], 0.f);
            }
        }
    }
}

extern "C" void kernel_launch(void* const* d_in, const int* in_sizes, int n_in,
                              void* d_out, int out_size, void* d_ws, size_t ws_size,
                              hipStream_t stream) {
    const float* X    = (const float*)d_in[0];
    const float* W    = (const float*)d_in[1];
    const int*   esrc = (const int*)d_in[2];
    const int*   edst = (const int*)d_in[3];
    const float* eval = (const float*)d_in[4];
    float* out = (float*)d_out;

    // workspace layout (16B-aligned)
    char* w = (char*)d_ws;
    unsigned short* Yb = (unsigned short*)w;  w += (size_t)N_NODES * M_IN * 2;  // 51.2 MB
    unsigned short* Xb = (unsigned short*)w;  w += (size_t)N_NODES * M_IN * 2;  // 51.2 MB
    unsigned short* Wt = (unsigned short*)w;  w += (size_t)M_IN * H_OUT * 2;    // 0.5 MB
    int*   offs   = (int*)w;                  w += (size_t)(N_NODES + 4) * 4;   // keep 16B align
    int*   cursor = (int*)w;                  w += (size_t)N_NODES * 4;
    unsigned int* pairs = (unsigned int*)w;                                     // 3.2 MB

    hipMemsetAsync(cursor, 0, N_NODES * sizeof(int), stream);

    prep_kernel<<<CONVX_B + CONVW_B + HIST_B, 256, 0, stream>>>(
        X, Xb, W, Wt, edst, cursor);

    scan_kernel<<<1, 1024, 0, stream>>>(cursor, offs);   // also zeroes cursor

    build_kernel<<<(N_EDGES + 255) / 256, 256, 0, stream>>>(
        esrc, edst, eval, offs, cursor, pairs);

    // 8 slices (xcd-pinned via bid%8) x 782 node-groups of 64 nodes; 2 passes
    const int GB = ((N_NODES + 63) / 64) * 8;            // 782*8 = 6256
    gather_kernel<<<GB, 256, 0, stream>>>(Xb, offs, pairs, Yb, 0);
    gather_kernel<<<GB, 256, 0, stream>>>(Xb, offs, pairs, Yb, 1);

    dim3 grid(H_OUT / BN, (N_NODES + BM - 1) / BM);      // (4, 391), col-tiles innermost
    gemm_mfma_kernel<<<grid, 256, 0, stream>>>(Yb, Wt, out);
}

// Round 7
// 278.679 us; speedup vs baseline: 1.6414x; 1.6414x over previous
//
#include <hip/hip_runtime.h>
#include <hip/hip_bf16.h>

#define N_NODES 50000
#define N_EDGES 800000
#define M_IN 512
#define H_OUT 512

typedef __attribute__((ext_vector_type(8))) short    bf16x8;  // MFMA A/B frag (4 VGPR)
typedef __attribute__((ext_vector_type(4))) float    f32x4;   // MFMA C/D frag
typedef __attribute__((ext_vector_type(8))) unsigned short u16x8;
typedef __attribute__((ext_vector_type(4))) unsigned short u16x4;

__device__ inline float bf2f(unsigned short u) {
    unsigned int x = ((unsigned int)u) << 16;
    return __builtin_bit_cast(float, x);
}
__device__ inline unsigned short f2bf(float f) {   // round-to-nearest-even
    unsigned int x = __builtin_bit_cast(unsigned int, f);
    return (unsigned short)((x + 0x7FFF + ((x >> 16) & 1)) >> 16);
}
__device__ inline void gload_lds16(const void* g, void* lds) {
    __builtin_amdgcn_global_load_lds(
        (const __attribute__((address_space(1))) void*)g,
        (__attribute__((address_space(3))) void*)lds, 16, 0, 0);
}
__device__ inline int wave_incl_scan(int x, int lane) {
#pragma unroll
    for (int d = 1; d < 64; d <<= 1) {
        int y = __shfl_up(x, d, 64);
        if (lane >= d) x += y;
    }
    return x;
}

// ---------------------------------------------------------------------------
// prep: fused convx (blocks [0,12500)) + convw + hist. All independent.
// ---------------------------------------------------------------------------
#define CONVX_B 12500
#define CONVW_B 1024
#define HIST_B  3125

__global__ __launch_bounds__(256) void prep_kernel(
    const float* __restrict__ X, unsigned short* __restrict__ Xb,
    const float* __restrict__ W, unsigned short* __restrict__ Wt,
    const int* __restrict__ edst, int* __restrict__ counts)
{
    const int b = blockIdx.x;
    if (b < CONVX_B) {
        const size_t i = (size_t)b * 256 + threadIdx.x;        // 3.2M threads x 8 f32
        const float4 a = ((const float4*)X)[2 * i];
        const float4 c = ((const float4*)X)[2 * i + 1];
        u16x8 o;
        o[0] = f2bf(a.x); o[1] = f2bf(a.y); o[2] = f2bf(a.z); o[3] = f2bf(a.w);
        o[4] = f2bf(c.x); o[5] = f2bf(c.y); o[6] = f2bf(c.z); o[7] = f2bf(c.w);
        *(u16x8*)(Xb + i * 8) = o;
    } else if (b < CONVX_B + CONVW_B) {
        const int id = (b - CONVX_B) * 256 + threadIdx.x;      // 262144 = 512*512
        const int n = id >> 9, k = id & 511;
        Wt[(size_t)n * 512 + k] = f2bf(W[(size_t)k * 512 + n]);
    } else {
        const int e = (b - CONVX_B - CONVW_B) * 256 + threadIdx.x;  // 800000 exact
        atomicAdd(&counts[edst[e]], 1);
    }
}

// ---------------------------------------------------------------------------
// Hierarchical scan (replaces the 110 µs single-block scan):
// scan1: 196 blocks -> per-block sums; scan2: 1 block scans 196 sums;
// scan3: 196 blocks -> local scan + block offset, writes offs, zeroes counts.
// ---------------------------------------------------------------------------
#define SCAN_B ((N_NODES + 255) / 256)   // 196

__global__ __launch_bounds__(256) void scan1_kernel(
    const int* __restrict__ counts, int* __restrict__ bsum)
{
    const int i = blockIdx.x * 256 + threadIdx.x;
    int v = (i < N_NODES) ? counts[i] : 0;
#pragma unroll
    for (int d = 1; d < 64; d <<= 1) v += __shfl_xor(v, d, 64);
    __shared__ int ws[4];
    if ((threadIdx.x & 63) == 0) ws[threadIdx.x >> 6] = v;
    __syncthreads();
    if (threadIdx.x == 0) bsum[blockIdx.x] = ws[0] + ws[1] + ws[2] + ws[3];
}

__global__ __launch_bounds__(256) void scan2_kernel(int* __restrict__ bsum)
{
    const int tid = threadIdx.x, lane = tid & 63, wv = tid >> 6;
    int v = (tid < SCAN_B) ? bsum[tid] : 0;
    int inc = wave_incl_scan(v, lane);
    __shared__ int ws[4];
    if (lane == 63) ws[wv] = inc;
    __syncthreads();
    if (tid == 0) {
        int run = 0;
#pragma unroll
        for (int k = 0; k < 4; ++k) { int t = ws[k]; ws[k] = run; run += t; }
    }
    __syncthreads();
    if (tid < SCAN_B) bsum[tid] = ws[wv] + inc - v;    // exclusive block prefix
}

__global__ __launch_bounds__(256) void scan3_kernel(
    int* __restrict__ counts, const int* __restrict__ bpre, int* __restrict__ offs)
{
    const int tid = threadIdx.x, lane = tid & 63, wv = tid >> 6;
    const int i = blockIdx.x * 256 + tid;
    int c = (i < N_NODES) ? counts[i] : 0;
    int inc = wave_incl_scan(c, lane);
    __shared__ int ws[4];
    if (lane == 63) ws[wv] = inc;
    __syncthreads();
    if (tid == 0) {
        int run = 0;
#pragma unroll
        for (int k = 0; k < 4; ++k) { int t = ws[k]; ws[k] = run; run += t; }
    }
    __syncthreads();
    const int excl = bpre[blockIdx.x] + ws[wv] + inc - c;
    if (i < N_NODES) {
        offs[i]   = excl;
        counts[i] = 0;                                  // becomes build cursor
        if (i == N_NODES - 1) offs[N_NODES] = excl + c; // == N_EDGES
    }
}

// build: packed edge = (src16 << 16) | bf16(val) — one 4B random store/edge.
__global__ __launch_bounds__(256) void build_kernel(
    const int* __restrict__ esrc, const int* __restrict__ edst,
    const float* __restrict__ eval,
    const int* __restrict__ offs, int* __restrict__ cursor,
    unsigned int* __restrict__ pairs)
{
    const int e = blockIdx.x * 256 + threadIdx.x;
    if (e >= N_EDGES) return;
    const int d   = edst[e];
    const int pos = offs[d] + atomicAdd(&cursor[d], 1);
    pairs[pos] = ((unsigned int)esrc[e] << 16) | (unsigned int)f2bf(eval[e]);
}

// ---------------------------------------------------------------------------
// Gather (round-5 champion): TWO waves per dst node, 256 cols each,
// 8 B/lane/edge, unroll-4. fp32 accum, bf16 out.
// ---------------------------------------------------------------------------
__global__ __launch_bounds__(256) void gather_kernel(
    const unsigned short* __restrict__ Xb,
    const int*          __restrict__ offs,
    const unsigned int* __restrict__ pairs,
    unsigned short*     __restrict__ Yb)
{
    const int gw   = blockIdx.x * 4 + (threadIdx.x >> 6);  // global wave id
    const int node = gw >> 1;
    const int half = gw & 1;
    const int lane = threadIdx.x & 63;
    if (node >= N_NODES) return;

    const int beg = offs[node];
    const int end = offs[node + 1];
    const int col = half * 256 + lane * 4;                 // first of 4 columns

    float a0 = 0.f, a1 = 0.f, a2 = 0.f, a3 = 0.f;

    int e = beg;
    for (; e + 3 < end; e += 4) {
        const unsigned int k0 = pairs[e],     k1 = pairs[e + 1];
        const unsigned int k2 = pairs[e + 2], k3 = pairs[e + 3];
        const u16x4 x0 = *(const u16x4*)(Xb + (size_t)(k0 >> 16) * M_IN + col);
        const u16x4 x1 = *(const u16x4*)(Xb + (size_t)(k1 >> 16) * M_IN + col);
        const u16x4 x2 = *(const u16x4*)(Xb + (size_t)(k2 >> 16) * M_IN + col);
        const u16x4 x3 = *(const u16x4*)(Xb + (size_t)(k3 >> 16) * M_IN + col);
        const float v0 = bf2f((unsigned short)(k0 & 0xffffu));
        const float v1 = bf2f((unsigned short)(k1 & 0xffffu));
        const float v2 = bf2f((unsigned short)(k2 & 0xffffu));
        const float v3 = bf2f((unsigned short)(k3 & 0xffffu));
        a0 += bf2f(x0[0]) * v0 + bf2f(x1[0]) * v1 + bf2f(x2[0]) * v2 + bf2f(x3[0]) * v3;
        a1 += bf2f(x0[1]) * v0 + bf2f(x1[1]) * v1 + bf2f(x2[1]) * v2 + bf2f(x3[1]) * v3;
        a2 += bf2f(x0[2]) * v0 + bf2f(x1[2]) * v1 + bf2f(x2[2]) * v2 + bf2f(x3[2]) * v3;
        a3 += bf2f(x0[3]) * v0 + bf2f(x1[3]) * v1 + bf2f(x2[3]) * v2 + bf2f(x3[3]) * v3;
    }
    for (; e < end; ++e) {
        const unsigned int k0 = pairs[e];
        const u16x4 x0 = *(const u16x4*)(Xb + (size_t)(k0 >> 16) * M_IN + col);
        const float v0 = bf2f((unsigned short)(k0 & 0xffffu));
        a0 += bf2f(x0[0]) * v0;
        a1 += bf2f(x0[1]) * v0;
        a2 += bf2f(x0[2]) * v0;
        a3 += bf2f(x0[3]) * v0;
    }

    u16x4 o;
    o[0] = f2bf(a0); o[1] = f2bf(a1); o[2] = f2bf(a2); o[3] = f2bf(a3);
    *(u16x4*)(Yb + (size_t)node * M_IN + col) = o;
}

// ---------------------------------------------------------------------------
// out = relu(Yb @ Wt^T) — bf16 MFMA 16x16x32, fp32 accum. (unchanged)
// 128x128 tile, BK=32, 4 waves, 2-phase double-buffered pipeline.
// ---------------------------------------------------------------------------
#define BM 128
#define BN 128
#define BK 32
#define NT (M_IN / BK)   // 16

__global__ __launch_bounds__(256, 2) void gemm_mfma_kernel(
    const unsigned short* __restrict__ Yb,
    const unsigned short* __restrict__ Wt,
    float* __restrict__ out)
{
    __shared__ unsigned short As[2][BM * BK];  // 2 x 8 KB
    __shared__ unsigned short Bs[2][BN * BK];  // 2 x 8 KB

    const int tid  = threadIdx.x;
    const int lane = tid & 63;
    const int wid  = tid >> 6;
    const int wr   = wid >> 1;
    const int wc   = wid & 1;
    const int row0 = blockIdx.y * BM;
    const int col0 = blockIdx.x * BN;

    f32x4 acc[4][4] = {};

    int srow[2], ksw[2], ldsb[2];
#pragma unroll
    for (int i = 0; i < 2; ++i) {
        const int b   = (i * 256 + tid) * 16;
        const int row = b >> 6;
        const int cir = (b >> 4) & 3;
        srow[i] = row;
        ksw[i]  = (cir ^ ((row >> 1) & 3)) << 3;
        ldsb[i] = b;
    }
    int agr[2];
#pragma unroll
    for (int i = 0; i < 2; ++i) {
        int gr = row0 + srow[i];
        if (gr >= N_NODES) gr = N_NODES - 1;
        agr[i] = gr;
    }

    int abyte[4], bbyte[4];
    const int c = lane >> 4;
#pragma unroll
    for (int m = 0; m < 4; ++m) {
        const int ra = wr * 64 + m * 16 + (lane & 15);
        abyte[m] = ra * 64 + ((c ^ ((ra >> 1) & 3)) << 4);
        const int rb = wc * 64 + m * 16 + (lane & 15);
        bbyte[m] = rb * 64 + ((c ^ ((rb >> 1) & 3)) << 4);
    }

#define STAGE(buf, k0)                                                          \
    do {                                                                        \
        _Pragma("unroll")                                                       \
        for (int i = 0; i < 2; ++i) {                                           \
            gload_lds16(Yb + (size_t)agr[i] * M_IN + (k0) + ksw[i],             \
                        (char*)As[buf] + ldsb[i]);                              \
            gload_lds16(Wt + (size_t)(col0 + srow[i]) * M_IN + (k0) + ksw[i],   \
                        (char*)Bs[buf] + ldsb[i]);                              \
        }                                                                       \
    } while (0)

    STAGE(0, 0);
    asm volatile("s_waitcnt vmcnt(0)" ::: "memory");
    __builtin_amdgcn_s_barrier();

    int cur = 0;
    for (int t = 0; t < NT; ++t) {
        if (t + 1 < NT) STAGE(cur ^ 1, (t + 1) * BK);

        bf16x8 af[4], bfr[4];
#pragma unroll
        for (int m = 0; m < 4; ++m)
            af[m]  = *(const bf16x8*)((const char*)As[cur] + abyte[m]);
#pragma unroll
        for (int n = 0; n < 4; ++n)
            bfr[n] = *(const bf16x8*)((const char*)Bs[cur] + bbyte[n]);

#pragma unroll
        for (int m = 0; m < 4; ++m)
#pragma unroll
            for (int n = 0; n < 4; ++n)
                acc[m][n] = __builtin_amdgcn_mfma_f32_16x16x32_bf16(
                    af[m], bfr[n], acc[m][n], 0, 0, 0);

        if (t + 1 < NT) {
            asm volatile("s_waitcnt vmcnt(0)" ::: "memory");
            __builtin_amdgcn_s_barrier();
        }
        cur ^= 1;
    }
#undef STAGE

    // epilogue: C/D map col=lane&15, row=(lane>>4)*4+r  [measured m89]
#pragma unroll
    for (int m = 0; m < 4; ++m) {
#pragma unroll
        for (int n = 0; n < 4; ++n) {
#pragma unroll
            for (int r = 0; r < 4; ++r) {
                const int row = row0 + wr * 64 + m * 16 + (lane >> 4) * 4 + r;
                const int col = col0 + wc * 64 + n * 16 + (lane & 15);
                if (row < N_NODES)
                    out[(size_t)row * H_OUT + col] = fmaxf(acc[m][n][r], 0.f);
            }
        }
    }
}

extern "C" void kernel_launch(void* const* d_in, const int* in_sizes, int n_in,
                              void* d_out, int out_size, void* d_ws, size_t ws_size,
                              hipStream_t stream) {
    const float* X    = (const float*)d_in[0];
    const float* W    = (const float*)d_in[1];
    const int*   esrc = (const int*)d_in[2];
    const int*   edst = (const int*)d_in[3];
    const float* eval = (const float*)d_in[4];
    float* out = (float*)d_out;

    // workspace layout (16B-aligned)
    char* w = (char*)d_ws;
    unsigned short* Yb = (unsigned short*)w;  w += (size_t)N_NODES * M_IN * 2;  // 51.2 MB
    unsigned short* Xb = (unsigned short*)w;  w += (size_t)N_NODES * M_IN * 2;  // 51.2 MB
    unsigned short* Wt = (unsigned short*)w;  w += (size_t)M_IN * H_OUT * 2;    // 0.5 MB
    int*   offs   = (int*)w;                  w += (size_t)(N_NODES + 4) * 4;   // 16B align
    int*   cursor = (int*)w;                  w += (size_t)N_NODES * 4;
    int*   bsum   = (int*)w;                  w += (size_t)((SCAN_B + 3) & ~3) * 4;
    unsigned int* pairs = (unsigned int*)w;                                     // 3.2 MB

    hipMemsetAsync(cursor, 0, N_NODES * sizeof(int), stream);

    prep_kernel<<<CONVX_B + CONVW_B + HIST_B, 256, 0, stream>>>(
        X, Xb, W, Wt, edst, cursor);

    scan1_kernel<<<SCAN_B, 256, 0, stream>>>(cursor, bsum);
    scan2_kernel<<<1, 256, 0, stream>>>(bsum);
    scan3_kernel<<<SCAN_B, 256, 0, stream>>>(cursor, bsum, offs);  // zeroes cursor

    build_kernel<<<(N_EDGES + 255) / 256, 256, 0, stream>>>(
        esrc, edst, eval, offs, cursor, pairs);

    // 2 waves per node -> 100000 waves -> 25000 blocks
    gather_kernel<<<(2 * N_NODES + 3) / 4, 256, 0, stream>>>(Xb, offs, pairs, Yb);

    dim3 grid(H_OUT / BN, (N_NODES + BM - 1) / BM);      // (4, 391)
    gemm_mfma_kernel<<<grid, 256, 0, stream>>>(Yb, Wt, out);
}